// Round 3
// baseline (765.422 us; speedup 1.0000x reference)
//
#include <hip/hip_runtime.h>

#define NU_ 100000
#define NI_ 50000
#define D_  128
#define C_  5
#define V_  200000
#define E_  200000
#define L_  10

typedef __bf16 bf16x8 __attribute__((ext_vector_type(8)));
typedef unsigned short u16;
typedef u16 u16x8 __attribute__((ext_vector_type(8)));
typedef float f32x4 __attribute__((ext_vector_type(4)));

// ws layout (bytes): [0..4) loss accumulator; [256..) swizzled bf16 weights
// (R1-proven envelope: 196 KB total ws usage, nothing else touched)
#define W1R_OFF 0
#define W2R_OFF 32768
#define W1T_OFF 49152
#define W2T_OFF 81920
#define WTOT    98304

__device__ __forceinline__ u16 f2bf(float x) {
    union { float f; unsigned int u; } v; v.f = x;
    unsigned int u = v.u;
    return (u16)((u + 0x7FFFu + ((u >> 16) & 1u)) >> 16);
}

// weights f32 -> bf16, MFMA-B-fragment swizzle: dest[((k>>3)*128+n)*8+(k&7)] = W[k*128+n]
__global__ void prep_kernel(const float* __restrict__ w1r, const float* __restrict__ w2r,
                            const float* __restrict__ w1t, const float* __restrict__ w2t,
                            u16* __restrict__ wbuf, float* __restrict__ loss_acc) {
    int idx = blockIdx.x * blockDim.x + threadIdx.x;
    if (idx == 0) *loss_acc = 0.f;
    if (idx >= WTOT) return;
    const float* src; int base;
    if (idx < W2R_OFF)      { src = w1r; base = W1R_OFF; }
    else if (idx < W1T_OFF) { src = w2r; base = W2R_OFF; }
    else if (idx < W2T_OFF) { src = w1t; base = W1T_OFF; }
    else                    { src = w2t; base = W2T_OFF; }
    int local = idx - base;
    int j = local & 7;
    int g = local >> 3;
    int n = g & 127;
    int kq = g >> 7;
    wbuf[idx] = f2bf(src[(kq * 8 + j) * 128 + n]);
}

// Stage 16 edges x 128 dims (one half of the concat input) into LDS A-frag layout:
// buf[(k8*16 + m)*8 + j]; lane: m=lane>>2, q=lane&3 covers dims q*32..q*32+31.
__device__ __forceinline__ void stage_half(const float* __restrict__ row, int lane, u16* buf) {
    int m = lane >> 2, q = lane & 3;
    const float* seg = row + q * 32;
#pragma unroll
    for (int i = 0; i < 4; i++) {
        float4 a = *(const float4*)(seg + i * 8);
        float4 b = *(const float4*)(seg + i * 8 + 4);
        u16x8 v;
        v[0] = f2bf(a.x); v[1] = f2bf(a.y); v[2] = f2bf(a.z); v[3] = f2bf(a.w);
        v[4] = f2bf(b.x); v[5] = f2bf(b.y); v[6] = f2bf(b.z); v[7] = f2bf(b.w);
        *(u16x8*)(buf + ((q * 4 + i) * 16 + m) * 8) = v;
    }
}

// 16x128 tile GEMM over K = KT*32; A frags from LDS, B frags from swizzled weights.
template <int KT>
__device__ __forceinline__ void gemm_tile(const u16* aLDS, const u16* __restrict__ Wg,
                                          int lq, int ln, f32x4 acc[8]) {
#pragma unroll
    for (int kt = 0; kt < KT; kt++) {
        bf16x8 af = *(const bf16x8*)(aLDS + ((kt * 4 + lq) * 16 + ln) * 8);
#pragma unroll
        for (int nt = 0; nt < 8; nt++) {
            bf16x8 bfv = *(const bf16x8*)(Wg + (size_t)((kt * 4 + lq) * 128 + nt * 16 + ln) * 8);
            acc[nt] = __builtin_amdgcn_mfma_f32_16x16x32_bf16(af, bfv, acc[nt], 0, 0, 0);
        }
    }
}

// relu(acc) -> LDS bf16 A-frag layout (next GEMM's A).
__device__ __forceinline__ void store_h_relu(const f32x4 acc[8], u16* buf, int lq, int ln) {
#pragma unroll
    for (int nt = 0; nt < 8; nt++)
#pragma unroll
        for (int reg = 0; reg < 4; reg++) {
            float h = fmaxf(acc[nt][reg], 0.f);
            int dcol = nt * 16 + ln;
            int r = lq * 4 + reg;
            buf[((dcol >> 3) * 16 + r) * 8 + (dcol & 7)] = f2bf(h);
        }
}

// One 2-layer MLP over concat([u[src],i[dst]]) staged as two K=128 halves.
__device__ __forceinline__ void mlp(const float* __restrict__ uF, const float* __restrict__ iF,
                                    const int* __restrict__ srcI, const int* __restrict__ dstI,
                                    int ebase, int lane, int lq, int ln,
                                    const u16* __restrict__ w1, const u16* __restrict__ w2,
                                    u16* bufA, u16* bufB, f32x4 acc[8]) {
    int e = ebase + (lane >> 2);
    int su = srcI[e], sd = dstI[e];
    f32x4 h1[8];
#pragma unroll
    for (int nt = 0; nt < 8; nt++) h1[nt] = (f32x4){0.f, 0.f, 0.f, 0.f};

    stage_half(uF + (size_t)su * D_, lane, bufA);
    __syncthreads();
    gemm_tile<4>(bufA, w1, lq, ln, h1);               // K 0..127
    __syncthreads();
    stage_half(iF + (size_t)sd * D_, lane, bufA);
    __syncthreads();
    gemm_tile<4>(bufA, w1 + 16384, lq, ln, h1);       // K 128..255
    store_h_relu(h1, bufB, lq, ln);
    __syncthreads();
    gemm_tile<4>(bufB, w2, lq, ln, acc);
}

__device__ __forceinline__ float softplus_(float x) {
    return fmaxf(x, 0.f) + log1pf(expf(-fabsf(x)));
}

__global__ __launch_bounds__(256, 5) void fused_kernel(
    const float* __restrict__ urf, const float* __restrict__ irf,
    const float* __restrict__ utf, const float* __restrict__ itf,
    const float* __restrict__ wp, const float* __restrict__ emb,
    const int* __restrict__ srcI, const int* __restrict__ dstI,
    const int* __restrict__ sidI, const int* __restrict__ nsidI,
    const u16* __restrict__ wbuf, float* __restrict__ loss_acc,
    float* __restrict__ out) {
    __shared__ u16 smem[4 * 4096];        // per wave: bufA 2048 + bufB 2048 u16 (8 KB)
    const int tid = threadIdx.x;
    const int w = tid >> 6;
    const int lane = tid & 63;
    const int lq = lane >> 4;
    const int ln = lane & 15;
    u16* bufA = smem + w * 4096;
    u16* bufB = bufA + 2048;
    const int ebase = blockIdx.x * 64 + w * 16;

    // ---------- rating path ----------
    f32x4 rh[8];
#pragma unroll
    for (int nt = 0; nt < 8; nt++) rh[nt] = (f32x4){0.f, 0.f, 0.f, 0.f};
    mlp(urf, irf, srcI, dstI, ebase, lane, lq, ln,
        wbuf + W1R_OFF, wbuf + W2R_OFF, bufA, bufB, rh);

    // ---------- pr = rh @ wp ----------
    {
        float pp[4][5];
#pragma unroll
        for (int r = 0; r < 4; r++)
#pragma unroll
            for (int c = 0; c < 5; c++) pp[r][c] = 0.f;
#pragma unroll
        for (int nt = 0; nt < 8; nt++) {
            int d = nt * 16 + ln;
            float wpc[5];
#pragma unroll
            for (int c = 0; c < 5; c++) wpc[c] = wp[d * 5 + c];
#pragma unroll
            for (int reg = 0; reg < 4; reg++)
#pragma unroll
                for (int c = 0; c < 5; c++) pp[reg][c] += rh[nt][reg] * wpc[c];
        }
#pragma unroll
        for (int off = 1; off < 16; off <<= 1)
#pragma unroll
            for (int reg = 0; reg < 4; reg++)
#pragma unroll
                for (int c = 0; c < 5; c++)
                    pp[reg][c] += __shfl_xor(pp[reg][c], off, 64);
        if (ln == 0) {
#pragma unroll
            for (int reg = 0; reg < 4; reg++) {
                int e = ebase + lq * 4 + reg;
#pragma unroll
                for (int c = 0; c < 5; c++) out[(size_t)e * 5 + c] = pp[reg][c];
            }
        }
    }

    // ---------- topic path (residual) ----------
    __syncthreads();
    f32x4 th[8];
#pragma unroll
    for (int nt = 0; nt < 8; nt++) th[nt] = rh[nt];
    mlp(utf, itf, srcI, dstI, ebase, lane, lq, ln,
        wbuf + W1T_OFF, wbuf + W2T_OFF, bufA, bufB, th);

    // th -> LDS f32 row-major (16x128 = 8 KB, overlays bufA+bufB)
    __syncthreads();
    float* thb = (float*)bufA;
#pragma unroll
    for (int nt = 0; nt < 8; nt++)
#pragma unroll
        for (int reg = 0; reg < 4; reg++)
            thb[(lq * 4 + reg) * 128 + nt * 16 + ln] = th[nt][reg];
    __syncthreads();

    // ---------- review gather + scores + loss ----------
    // half-wave (32-lane) per edge; float4 per lane -> 2 emb rows in flight per
    // wave load instruction (vs 1 with float2), half the load-issue count.
    float wave_loss = 0.f;
    const int h = lane >> 5, hl = lane & 31;
    for (int mp = 0; mp < 16; mp += 2) {
        int m = mp + h;
        int e = ebase + m;
        float4 t4 = *(const float4*)(thb + m * 128 + hl * 4);
        const int* sp = sidI + e * L_;
        const int* np = nsidI + e * L_;
        float ps = 0.f, ns = 0.f;
        int pcnt = 0, ncnt = 0;
#pragma unroll
        for (int i = 0; i < L_; i++) {
            int s = sp[i];
            pcnt += (s > 0) ? 1 : 0;
            float4 ev = *(const float4*)(emb + (size_t)s * D_ + hl * 4);
            ps += t4.x * ev.x + t4.y * ev.y + t4.z * ev.z + t4.w * ev.w;
        }
#pragma unroll
        for (int i = 0; i < L_; i++) {
            int s = np[i];
            ncnt += (s > 0) ? 1 : 0;
            float4 ev = *(const float4*)(emb + (size_t)s * D_ + hl * 4);
            ns += t4.x * ev.x + t4.y * ev.y + t4.z * ev.z + t4.w * ev.w;
        }
#pragma unroll
        for (int off = 1; off < 32; off <<= 1) {
            ps += __shfl_xor(ps, off, 64);
            ns += __shfl_xor(ns, off, 64);
        }
        if (hl == 0) {
            ps /= ((float)pcnt + 1e-9f);
            ns /= ((float)ncnt + 1e-9f);
            wave_loss += softplus_(ns - ps);
        }
    }
    wave_loss += __shfl_xor(wave_loss, 32, 64);
    if (lane == 0) atomicAdd(loss_acc, wave_loss);
}

__global__ void finish_kernel(const float* __restrict__ loss_acc, float* __restrict__ out) {
    float v = loss_acc[0] * (1.0f / (float)E_);
    out[(size_t)E_ * C_]     = v;
    out[(size_t)E_ * C_ + 1] = v;
}

extern "C" void kernel_launch(void* const* d_in, const int* in_sizes, int n_in,
                              void* d_out, int out_size, void* d_ws, size_t ws_size,
                              hipStream_t stream) {
    const float* urf = (const float*)d_in[0];
    const float* irf = (const float*)d_in[1];
    const float* utf = (const float*)d_in[2];
    const float* itf = (const float*)d_in[3];
    const float* w1r = (const float*)d_in[4];
    const float* w2r = (const float*)d_in[5];
    const float* w1t = (const float*)d_in[6];
    const float* w2t = (const float*)d_in[7];
    const float* wp  = (const float*)d_in[8];
    const float* emb = (const float*)d_in[9];
    const int* srcI  = (const int*)d_in[10];
    const int* dstI  = (const int*)d_in[11];
    const int* sidI  = (const int*)d_in[12];
    const int* nsidI = (const int*)d_in[13];
    float* out = (float*)d_out;

    float* loss_acc = (float*)d_ws;
    u16* wbuf = (u16*)((char*)d_ws + 256);

    prep_kernel<<<(WTOT + 255) / 256, 256, 0, stream>>>(w1r, w2r, w1t, w2t, wbuf, loss_acc);
    fused_kernel<<<E_ / 64, 256, 0, stream>>>(urf, irf, utf, itf, wp, emb,
                                              srcI, dstI, sidI, nsidI,
                                              wbuf, loss_acc, out);
    finish_kernel<<<1, 1, 0, stream>>>(loss_acc, out);
}

// Round 4
// 662.925 us; speedup vs baseline: 1.1546x; 1.1546x over previous
//
#include <hip/hip_runtime.h>

#define NU_ 100000
#define NI_ 50000
#define D_  128
#define C_  5
#define V_  200000
#define E_  200000
#define L_  10

typedef __bf16 bf16x8 __attribute__((ext_vector_type(8)));
typedef unsigned short u16;
typedef u16 u16x8 __attribute__((ext_vector_type(8)));
typedef float f32x4 __attribute__((ext_vector_type(4)));

// ws layout (bytes): [0..4) loss accumulator; [256..) swizzled bf16 weights
#define W1R_OFF 0
#define W2R_OFF 32768
#define W1T_OFF 49152
#define W2T_OFF 81920
#define WTOT    98304

__device__ __forceinline__ u16 f2bf(float x) {
    union { float f; unsigned int u; } v; v.f = x;
    unsigned int u = v.u;
    return (u16)((u + 0x7FFFu + ((u >> 16) & 1u)) >> 16);
}

// weights f32 -> bf16, MFMA-B-fragment swizzle: dest[((k>>3)*128+n)*8+(k&7)] = W[k*128+n]
__global__ void prep_kernel(const float* __restrict__ w1r, const float* __restrict__ w2r,
                            const float* __restrict__ w1t, const float* __restrict__ w2t,
                            u16* __restrict__ wbuf, float* __restrict__ loss_acc) {
    int idx = blockIdx.x * blockDim.x + threadIdx.x;
    if (idx == 0) *loss_acc = 0.f;
    if (idx >= WTOT) return;
    const float* src; int base;
    if (idx < W2R_OFF)      { src = w1r; base = W1R_OFF; }
    else if (idx < W1T_OFF) { src = w2r; base = W2R_OFF; }
    else if (idx < W2T_OFF) { src = w1t; base = W1T_OFF; }
    else                    { src = w2t; base = W2T_OFF; }
    int local = idx - base;
    int j = local & 7;
    int g = local >> 3;
    int n = g & 127;
    int kq = g >> 7;
    wbuf[idx] = f2bf(src[(kq * 8 + j) * 128 + n]);
}

// Stage 16 edges x 128 dims (one half of the concat input) into LDS A-frag layout:
// buf[(k8*16 + m)*8 + j]; lane: m=lane>>2, q=lane&3 covers dims q*32..q*32+31.
__device__ __forceinline__ void stage_half(const float* __restrict__ row, int lane, u16* buf) {
    int m = lane >> 2, q = lane & 3;
    const float* seg = row + q * 32;
#pragma unroll
    for (int i = 0; i < 4; i++) {
        float4 a = *(const float4*)(seg + i * 8);
        float4 b = *(const float4*)(seg + i * 8 + 4);
        u16x8 v;
        v[0] = f2bf(a.x); v[1] = f2bf(a.y); v[2] = f2bf(a.z); v[3] = f2bf(a.w);
        v[4] = f2bf(b.x); v[5] = f2bf(b.y); v[6] = f2bf(b.z); v[7] = f2bf(b.w);
        *(u16x8*)(buf + ((q * 4 + i) * 16 + m) * 8) = v;
    }
}

// 16x128 tile GEMM over K = KT*32; A frags from LDS, B frags from swizzled weights.
template <int KT>
__device__ __forceinline__ void gemm_tile(const u16* aLDS, const u16* __restrict__ Wg,
                                          int lq, int ln, f32x4 acc[8]) {
#pragma unroll
    for (int kt = 0; kt < KT; kt++) {
        bf16x8 af = *(const bf16x8*)(aLDS + ((kt * 4 + lq) * 16 + ln) * 8);
#pragma unroll
        for (int nt = 0; nt < 8; nt++) {
            bf16x8 bfv = *(const bf16x8*)(Wg + (size_t)((kt * 4 + lq) * 128 + nt * 16 + ln) * 8);
            acc[nt] = __builtin_amdgcn_mfma_f32_16x16x32_bf16(af, bfv, acc[nt], 0, 0, 0);
        }
    }
}

// relu(acc) -> LDS bf16 A-frag layout (next GEMM's A).
__device__ __forceinline__ void store_h_relu(const f32x4 acc[8], u16* buf, int lq, int ln) {
#pragma unroll
    for (int nt = 0; nt < 8; nt++)
#pragma unroll
        for (int reg = 0; reg < 4; reg++) {
            float h = fmaxf(acc[nt][reg], 0.f);
            int dcol = nt * 16 + ln;
            int r = lq * 4 + reg;
            buf[((dcol >> 3) * 16 + r) * 8 + (dcol & 7)] = f2bf(h);
        }
}

// One 2-layer MLP over concat([u[src],i[dst]]) staged as two K=128 halves.
__device__ __forceinline__ void mlp(const float* __restrict__ uF, const float* __restrict__ iF,
                                    const int* __restrict__ srcI, const int* __restrict__ dstI,
                                    int ebase, int lane, int lq, int ln,
                                    const u16* __restrict__ w1, const u16* __restrict__ w2,
                                    u16* bufA, u16* bufB, f32x4 acc[8]) {
    int e = ebase + (lane >> 2);
    int su = srcI[e], sd = dstI[e];
    f32x4 h1[8];
#pragma unroll
    for (int nt = 0; nt < 8; nt++) h1[nt] = (f32x4){0.f, 0.f, 0.f, 0.f};

    stage_half(uF + (size_t)su * D_, lane, bufA);
    __syncthreads();
    gemm_tile<4>(bufA, w1, lq, ln, h1);               // K 0..127
    __syncthreads();
    stage_half(iF + (size_t)sd * D_, lane, bufA);
    __syncthreads();
    gemm_tile<4>(bufA, w1 + 16384, lq, ln, h1);       // K 128..255
    store_h_relu(h1, bufB, lq, ln);
    __syncthreads();
    gemm_tile<4>(bufB, w2, lq, ln, acc);
}

__device__ __forceinline__ float softplus_(float x) {
    return fmaxf(x, 0.f) + log1pf(expf(-fabsf(x)));
}

// launch_bounds: (256,5) forced VGPR<=~102, compiler chose 48 -> ~285 MB scratch
// spill traffic (R3 WRITE_SIZE). (256,4) caps at 128 >= ~100 live regs: no spill.
__global__ __launch_bounds__(256, 4) void fused_kernel(
    const float* __restrict__ urf, const float* __restrict__ irf,
    const float* __restrict__ utf, const float* __restrict__ itf,
    const float* __restrict__ wp, const float* __restrict__ emb,
    const int* __restrict__ srcI, const int* __restrict__ dstI,
    const int* __restrict__ sidI, const int* __restrict__ nsidI,
    const u16* __restrict__ wbuf, float* __restrict__ loss_acc,
    float* __restrict__ out) {
    __shared__ u16 smem[4 * 4096];        // per wave: bufA 2048 + bufB 2048 u16 (8 KB)
    const int tid = threadIdx.x;
    const int w = tid >> 6;
    const int lane = tid & 63;
    const int lq = lane >> 4;
    const int ln = lane & 15;
    u16* bufA = smem + w * 4096;
    u16* bufB = bufA + 2048;
    const int ebase = blockIdx.x * 64 + w * 16;

    // ---------- rating path ----------
    f32x4 rh[8];
#pragma unroll
    for (int nt = 0; nt < 8; nt++) rh[nt] = (f32x4){0.f, 0.f, 0.f, 0.f};
    mlp(urf, irf, srcI, dstI, ebase, lane, lq, ln,
        wbuf + W1R_OFF, wbuf + W2R_OFF, bufA, bufB, rh);

    // ---------- pr = rh @ wp ----------
    {
        float pp[4][5];
#pragma unroll
        for (int r = 0; r < 4; r++)
#pragma unroll
            for (int c = 0; c < 5; c++) pp[r][c] = 0.f;
#pragma unroll
        for (int nt = 0; nt < 8; nt++) {
            int d = nt * 16 + ln;
            float wpc[5];
#pragma unroll
            for (int c = 0; c < 5; c++) wpc[c] = wp[d * 5 + c];
#pragma unroll
            for (int reg = 0; reg < 4; reg++)
#pragma unroll
                for (int c = 0; c < 5; c++) pp[reg][c] += rh[nt][reg] * wpc[c];
        }
#pragma unroll
        for (int off = 1; off < 16; off <<= 1)
#pragma unroll
            for (int reg = 0; reg < 4; reg++)
#pragma unroll
                for (int c = 0; c < 5; c++)
                    pp[reg][c] += __shfl_xor(pp[reg][c], off, 64);
        if (ln == 0) {
#pragma unroll
            for (int reg = 0; reg < 4; reg++) {
                int e = ebase + lq * 4 + reg;
#pragma unroll
                for (int c = 0; c < 5; c++) out[(size_t)e * 5 + c] = pp[reg][c];
            }
        }
    }

    // ---------- topic path (residual) ----------
    __syncthreads();
    f32x4 th[8];
#pragma unroll
    for (int nt = 0; nt < 8; nt++) th[nt] = rh[nt];
    mlp(utf, itf, srcI, dstI, ebase, lane, lq, ln,
        wbuf + W1T_OFF, wbuf + W2T_OFF, bufA, bufB, th);

    // th -> LDS f32 row-major (16x128 = 8 KB, overlays bufA+bufB)
    __syncthreads();
    float* thb = (float*)bufA;
#pragma unroll
    for (int nt = 0; nt < 8; nt++)
#pragma unroll
        for (int reg = 0; reg < 4; reg++)
            thb[(lq * 4 + reg) * 128 + nt * 16 + ln] = th[nt][reg];
    __syncthreads();

    // ---------- review gather + scores + loss ----------
    // half-wave (32-lane) per edge; float4 per lane -> 2 emb rows in flight per
    // wave load instruction.
    float wave_loss = 0.f;
    const int h = lane >> 5, hl = lane & 31;
    for (int mp = 0; mp < 16; mp += 2) {
        int m = mp + h;
        int e = ebase + m;
        float4 t4 = *(const float4*)(thb + m * 128 + hl * 4);
        const int* sp = sidI + e * L_;
        const int* np = nsidI + e * L_;
        float ps = 0.f, ns = 0.f;
        int pcnt = 0, ncnt = 0;
#pragma unroll
        for (int i = 0; i < L_; i++) {
            int s = sp[i];
            pcnt += (s > 0) ? 1 : 0;
            float4 ev = *(const float4*)(emb + (size_t)s * D_ + hl * 4);
            ps += t4.x * ev.x + t4.y * ev.y + t4.z * ev.z + t4.w * ev.w;
        }
#pragma unroll
        for (int i = 0; i < L_; i++) {
            int s = np[i];
            ncnt += (s > 0) ? 1 : 0;
            float4 ev = *(const float4*)(emb + (size_t)s * D_ + hl * 4);
            ns += t4.x * ev.x + t4.y * ev.y + t4.z * ev.z + t4.w * ev.w;
        }
#pragma unroll
        for (int off = 1; off < 32; off <<= 1) {
            ps += __shfl_xor(ps, off, 64);
            ns += __shfl_xor(ns, off, 64);
        }
        if (hl == 0) {
            ps /= ((float)pcnt + 1e-9f);
            ns /= ((float)ncnt + 1e-9f);
            wave_loss += softplus_(ns - ps);
        }
    }
    wave_loss += __shfl_xor(wave_loss, 32, 64);
    if (lane == 0) atomicAdd(loss_acc, wave_loss);
}

__global__ void finish_kernel(const float* __restrict__ loss_acc, float* __restrict__ out) {
    float v = loss_acc[0] * (1.0f / (float)E_);
    out[(size_t)E_ * C_]     = v;
    out[(size_t)E_ * C_ + 1] = v;
}

extern "C" void kernel_launch(void* const* d_in, const int* in_sizes, int n_in,
                              void* d_out, int out_size, void* d_ws, size_t ws_size,
                              hipStream_t stream) {
    const float* urf = (const float*)d_in[0];
    const float* irf = (const float*)d_in[1];
    const float* utf = (const float*)d_in[2];
    const float* itf = (const float*)d_in[3];
    const float* w1r = (const float*)d_in[4];
    const float* w2r = (const float*)d_in[5];
    const float* w1t = (const float*)d_in[6];
    const float* w2t = (const float*)d_in[7];
    const float* wp  = (const float*)d_in[8];
    const float* emb = (const float*)d_in[9];
    const int* srcI  = (const int*)d_in[10];
    const int* dstI  = (const int*)d_in[11];
    const int* sidI  = (const int*)d_in[12];
    const int* nsidI = (const int*)d_in[13];
    float* out = (float*)d_out;

    float* loss_acc = (float*)d_ws;
    u16* wbuf = (u16*)((char*)d_ws + 256);

    prep_kernel<<<(WTOT + 255) / 256, 256, 0, stream>>>(w1r, w2r, w1t, w2t, wbuf, loss_acc);
    fused_kernel<<<E_ / 64, 256, 0, stream>>>(urf, irf, utf, itf, wp, emb,
                                              srcI, dstI, sidI, nsidI,
                                              wbuf, loss_acc, out);
    finish_kernel<<<1, 1, 0, stream>>>(loss_acc, out);
}

// Round 5
// 647.746 us; speedup vs baseline: 1.1817x; 1.0234x over previous
//
#include <hip/hip_runtime.h>

#define NU_ 100000
#define NI_ 50000
#define D_  128
#define C_  5
#define V_  200000
#define E_  200000
#define L_  10

typedef __bf16 bf16x8 __attribute__((ext_vector_type(8)));
typedef unsigned short u16;
typedef u16 u16x8 __attribute__((ext_vector_type(8)));
typedef float f32x4 __attribute__((ext_vector_type(4)));

// ws layout (bytes): [0..4) loss accumulator; [256..) swizzled bf16 weights
#define W1R_OFF 0
#define W2R_OFF 32768
#define W1T_OFF 49152
#define W2T_OFF 81920
#define WTOT    98304

__device__ __forceinline__ u16 f2bf(float x) {
    union { float f; unsigned int u; } v; v.f = x;
    unsigned int u = v.u;
    return (u16)((u + 0x7FFFu + ((u >> 16) & 1u)) >> 16);
}

// weights f32 -> bf16, MFMA-B-fragment swizzle: dest[((k>>3)*128+n)*8+(k&7)] = W[k*128+n]
__global__ void prep_kernel(const float* __restrict__ w1r, const float* __restrict__ w2r,
                            const float* __restrict__ w1t, const float* __restrict__ w2t,
                            u16* __restrict__ wbuf, float* __restrict__ loss_acc) {
    int idx = blockIdx.x * blockDim.x + threadIdx.x;
    if (idx == 0) *loss_acc = 0.f;
    if (idx >= WTOT) return;
    const float* src; int base;
    if (idx < W2R_OFF)      { src = w1r; base = W1R_OFF; }
    else if (idx < W1T_OFF) { src = w2r; base = W2R_OFF; }
    else if (idx < W2T_OFF) { src = w1t; base = W1T_OFF; }
    else                    { src = w2t; base = W2T_OFF; }
    int local = idx - base;
    int j = local & 7;
    int g = local >> 3;
    int n = g & 127;
    int kq = g >> 7;
    wbuf[idx] = f2bf(src[(kq * 8 + j) * 128 + n]);
}

// Stage 16 edges x 128 dims (one half of the concat input) into LDS A-frag layout:
// buf[(k8*16 + m)*8 + j]; lane: m=lane>>2, q=lane&3 covers dims q*32..q*32+31.
__device__ __forceinline__ void stage_half(const float* __restrict__ row, int lane, u16* buf) {
    int m = lane >> 2, q = lane & 3;
    const float* seg = row + q * 32;
#pragma unroll
    for (int i = 0; i < 4; i++) {
        float4 a = *(const float4*)(seg + i * 8);
        float4 b = *(const float4*)(seg + i * 8 + 4);
        u16x8 v;
        v[0] = f2bf(a.x); v[1] = f2bf(a.y); v[2] = f2bf(a.z); v[3] = f2bf(a.w);
        v[4] = f2bf(b.x); v[5] = f2bf(b.y); v[6] = f2bf(b.z); v[7] = f2bf(b.w);
        *(u16x8*)(buf + ((q * 4 + i) * 16 + m) * 8) = v;
    }
}

// 16x128 tile GEMM over K = KT*32; A frags from LDS, B frags from swizzled weights.
template <int KT>
__device__ __forceinline__ void gemm_tile(const u16* aLDS, const u16* __restrict__ Wg,
                                          int lq, int ln, f32x4 acc[8]) {
#pragma unroll
    for (int kt = 0; kt < KT; kt++) {
        bf16x8 af = *(const bf16x8*)(aLDS + ((kt * 4 + lq) * 16 + ln) * 8);
#pragma unroll
        for (int nt = 0; nt < 8; nt++) {
            bf16x8 bfv = *(const bf16x8*)(Wg + (size_t)((kt * 4 + lq) * 128 + nt * 16 + ln) * 8);
            acc[nt] = __builtin_amdgcn_mfma_f32_16x16x32_bf16(af, bfv, acc[nt], 0, 0, 0);
        }
    }
}

// relu(acc) -> LDS bf16 A-frag layout (next GEMM's A).
__device__ __forceinline__ void store_h_relu(const f32x4 acc[8], u16* buf, int lq, int ln) {
#pragma unroll
    for (int nt = 0; nt < 8; nt++)
#pragma unroll
        for (int reg = 0; reg < 4; reg++) {
            float h = fmaxf(acc[nt][reg], 0.f);
            int dcol = nt * 16 + ln;
            int r = lq * 4 + reg;
            buf[((dcol >> 3) * 16 + r) * 8 + (dcol & 7)] = f2bf(h);
        }
}

// One 2-layer MLP over concat([u[src],i[dst]]) staged as two K=128 halves.
__device__ __forceinline__ void mlp(const float* __restrict__ uF, const float* __restrict__ iF,
                                    const int* __restrict__ srcI, const int* __restrict__ dstI,
                                    int ebase, int lane, int lq, int ln,
                                    const u16* __restrict__ w1, const u16* __restrict__ w2,
                                    u16* bufA, u16* bufB, f32x4 acc[8]) {
    int e = ebase + (lane >> 2);
    int su = srcI[e], sd = dstI[e];
    f32x4 h1[8];
#pragma unroll
    for (int nt = 0; nt < 8; nt++) h1[nt] = (f32x4){0.f, 0.f, 0.f, 0.f};

    stage_half(uF + (size_t)su * D_, lane, bufA);
    __syncthreads();
    gemm_tile<4>(bufA, w1, lq, ln, h1);               // K 0..127
    __syncthreads();
    stage_half(iF + (size_t)sd * D_, lane, bufA);
    __syncthreads();
    gemm_tile<4>(bufA, w1 + 16384, lq, ln, h1);       // K 128..255
    store_h_relu(h1, bufB, lq, ln);
    __syncthreads();
    gemm_tile<4>(bufB, w2, lq, ln, acc);
}

__device__ __forceinline__ float softplus_(float x) {
    return fmaxf(x, 0.f) + log1pf(expf(-fabsf(x)));
}

// launch_bounds evidence: (256,3) -> 84 VGPR, no spill (R1); (256,4) -> 64 VGPR,
// 104 MB spill (R4); (256,5) -> 48 VGPR, 290 MB spill (R3). The allocator
// under-allocates and spills for anything tighter than (256,3).
__global__ __launch_bounds__(256, 3) void fused_kernel(
    const float* __restrict__ urf, const float* __restrict__ irf,
    const float* __restrict__ utf, const float* __restrict__ itf,
    const float* __restrict__ wp, const float* __restrict__ emb,
    const int* __restrict__ srcI, const int* __restrict__ dstI,
    const int* __restrict__ sidI, const int* __restrict__ nsidI,
    const u16* __restrict__ wbuf, float* __restrict__ loss_acc,
    float* __restrict__ out) {
    __shared__ u16 smem[4 * 4096];        // per wave: bufA 2048 + bufB 2048 u16 (8 KB)
    const int tid = threadIdx.x;
    const int w = tid >> 6;
    const int lane = tid & 63;
    const int lq = lane >> 4;
    const int ln = lane & 15;
    u16* bufA = smem + w * 4096;
    u16* bufB = bufA + 2048;
    const int ebase = blockIdx.x * 64 + w * 16;

    // ---------- rating path ----------
    f32x4 rh[8];
#pragma unroll
    for (int nt = 0; nt < 8; nt++) rh[nt] = (f32x4){0.f, 0.f, 0.f, 0.f};
    mlp(urf, irf, srcI, dstI, ebase, lane, lq, ln,
        wbuf + W1R_OFF, wbuf + W2R_OFF, bufA, bufB, rh);

    // ---------- pr = rh @ wp ----------
    {
        float pp[4][5];
#pragma unroll
        for (int r = 0; r < 4; r++)
#pragma unroll
            for (int c = 0; c < 5; c++) pp[r][c] = 0.f;
#pragma unroll
        for (int nt = 0; nt < 8; nt++) {
            int d = nt * 16 + ln;
            float wpc[5];
#pragma unroll
            for (int c = 0; c < 5; c++) wpc[c] = wp[d * 5 + c];
#pragma unroll
            for (int reg = 0; reg < 4; reg++)
#pragma unroll
                for (int c = 0; c < 5; c++) pp[reg][c] += rh[nt][reg] * wpc[c];
        }
#pragma unroll
        for (int off = 1; off < 16; off <<= 1)
#pragma unroll
            for (int reg = 0; reg < 4; reg++)
#pragma unroll
                for (int c = 0; c < 5; c++)
                    pp[reg][c] += __shfl_xor(pp[reg][c], off, 64);
        if (ln == 0) {
#pragma unroll
            for (int reg = 0; reg < 4; reg++) {
                int e = ebase + lq * 4 + reg;
#pragma unroll
                for (int c = 0; c < 5; c++) out[(size_t)e * 5 + c] = pp[reg][c];
            }
        }
    }

    // ---------- topic path (residual) ----------
    __syncthreads();
    f32x4 th[8];
#pragma unroll
    for (int nt = 0; nt < 8; nt++) th[nt] = rh[nt];
    mlp(utf, itf, srcI, dstI, ebase, lane, lq, ln,
        wbuf + W1T_OFF, wbuf + W2T_OFF, bufA, bufB, th);

    // th -> LDS f32 row-major (16x128 = 8 KB, overlays bufA+bufB)
    __syncthreads();
    float* thb = (float*)bufA;
#pragma unroll
    for (int nt = 0; nt < 8; nt++)
#pragma unroll
        for (int reg = 0; reg < 4; reg++)
            thb[(lq * 4 + reg) * 128 + nt * 16 + ln] = th[nt][reg];
    __syncthreads();

    // ---------- review gather + scores + loss ----------
    // half-wave (32-lane) per edge; float4 per lane -> 2 emb rows in flight per
    // wave load instruction.
    float wave_loss = 0.f;
    const int h = lane >> 5, hl = lane & 31;
    for (int mp = 0; mp < 16; mp += 2) {
        int m = mp + h;
        int e = ebase + m;
        float4 t4 = *(const float4*)(thb + m * 128 + hl * 4);
        const int* sp = sidI + e * L_;
        const int* np = nsidI + e * L_;
        float ps = 0.f, ns = 0.f;
        int pcnt = 0, ncnt = 0;
#pragma unroll
        for (int i = 0; i < L_; i++) {
            int s = sp[i];
            pcnt += (s > 0) ? 1 : 0;
            float4 ev = *(const float4*)(emb + (size_t)s * D_ + hl * 4);
            ps += t4.x * ev.x + t4.y * ev.y + t4.z * ev.z + t4.w * ev.w;
        }
#pragma unroll
        for (int i = 0; i < L_; i++) {
            int s = np[i];
            ncnt += (s > 0) ? 1 : 0;
            float4 ev = *(const float4*)(emb + (size_t)s * D_ + hl * 4);
            ns += t4.x * ev.x + t4.y * ev.y + t4.z * ev.z + t4.w * ev.w;
        }
#pragma unroll
        for (int off = 1; off < 32; off <<= 1) {
            ps += __shfl_xor(ps, off, 64);
            ns += __shfl_xor(ns, off, 64);
        }
        if (hl == 0) {
            ps /= ((float)pcnt + 1e-9f);
            ns /= ((float)ncnt + 1e-9f);
            wave_loss += softplus_(ns - ps);
        }
    }
    wave_loss += __shfl_xor(wave_loss, 32, 64);
    if (lane == 0) atomicAdd(loss_acc, wave_loss);
}

__global__ void finish_kernel(const float* __restrict__ loss_acc, float* __restrict__ out) {
    float v = loss_acc[0] * (1.0f / (float)E_);
    out[(size_t)E_ * C_]     = v;
    out[(size_t)E_ * C_ + 1] = v;
}

extern "C" void kernel_launch(void* const* d_in, const int* in_sizes, int n_in,
                              void* d_out, int out_size, void* d_ws, size_t ws_size,
                              hipStream_t stream) {
    const float* urf = (const float*)d_in[0];
    const float* irf = (const float*)d_in[1];
    const float* utf = (const float*)d_in[2];
    const float* itf = (const float*)d_in[3];
    const float* w1r = (const float*)d_in[4];
    const float* w2r = (const float*)d_in[5];
    const float* w1t = (const float*)d_in[6];
    const float* w2t = (const float*)d_in[7];
    const float* wp  = (const float*)d_in[8];
    const float* emb = (const float*)d_in[9];
    const int* srcI  = (const int*)d_in[10];
    const int* dstI  = (const int*)d_in[11];
    const int* sidI  = (const int*)d_in[12];
    const int* nsidI = (const int*)d_in[13];
    float* out = (float*)d_out;

    float* loss_acc = (float*)d_ws;
    u16* wbuf = (u16*)((char*)d_ws + 256);

    prep_kernel<<<(WTOT + 255) / 256, 256, 0, stream>>>(w1r, w2r, w1t, w2t, wbuf, loss_acc);
    fused_kernel<<<E_ / 64, 256, 0, stream>>>(urf, irf, utf, itf, wp, emb,
                                              srcI, dstI, sidI, nsidI,
                                              wbuf, loss_acc, out);
    finish_kernel<<<1, 1, 0, stream>>>(loss_acc, out);
}

// Round 6
// 588.663 us; speedup vs baseline: 1.3003x; 1.1004x over previous
//
#include <hip/hip_runtime.h>

#define NU_ 100000
#define NI_ 50000
#define D_  128
#define C_  5
#define V_  200000
#define E_  200000
#define L_  10

typedef __bf16 bf16x8 __attribute__((ext_vector_type(8)));
typedef unsigned short u16;
typedef u16 u16x8 __attribute__((ext_vector_type(8)));
typedef float f32x4 __attribute__((ext_vector_type(4)));

// ws layout (bytes): [0..4) loss acc; [256..) swizzled bf16 weights (196 KB);
// [256K..) embB = V*D bf16 (51.2 MB), guarded by ws_size check.
#define W1R_OFF 0
#define W2R_OFF 32768
#define W1T_OFF 49152
#define W2T_OFF 81920
#define WTOT    98304
#define EMB_BYTE_OFF (256 * 1024)
#define EMB_ELEMS    (V_ * D_)

__device__ __forceinline__ u16 f2bf(float x) {
    union { float f; unsigned int u; } v; v.f = x;
    unsigned int u = v.u;
    return (u16)((u + 0x7FFFu + ((u >> 16) & 1u)) >> 16);
}
__device__ __forceinline__ float bfhi(unsigned int u) {
    union { unsigned int u; float f; } v; v.u = u & 0xFFFF0000u; return v.f;
}
__device__ __forceinline__ float bflo(unsigned int u) {
    union { unsigned int u; float f; } v; v.u = u << 16; return v.f;
}

// weights f32 -> bf16, MFMA-B-fragment swizzle: dest[((k>>3)*128+n)*8+(k&7)] = W[k*128+n]
__global__ void prep_kernel(const float* __restrict__ w1r, const float* __restrict__ w2r,
                            const float* __restrict__ w1t, const float* __restrict__ w2t,
                            u16* __restrict__ wbuf, float* __restrict__ loss_acc) {
    int idx = blockIdx.x * blockDim.x + threadIdx.x;
    if (idx == 0) *loss_acc = 0.f;
    if (idx >= WTOT) return;
    const float* src; int base;
    if (idx < W2R_OFF)      { src = w1r; base = W1R_OFF; }
    else if (idx < W1T_OFF) { src = w2r; base = W2R_OFF; }
    else if (idx < W2T_OFF) { src = w1t; base = W1T_OFF; }
    else                    { src = w2t; base = W2T_OFF; }
    int local = idx - base;
    int j = local & 7;
    int g = local >> 3;
    int n = g & 127;
    int kq = g >> 7;
    wbuf[idx] = f2bf(src[(kq * 8 + j) * 128 + n]);
}

// bulk f32 -> bf16 convert, 8 elems/thread (used for emb only: 51.2 MB)
__global__ void cvt_kernel(const float* __restrict__ src, u16* __restrict__ dst, int n8) {
    int i = blockIdx.x * blockDim.x + threadIdx.x;
    if (i >= n8) return;
    float4 a = *(const float4*)(src + (size_t)i * 8);
    float4 b = *(const float4*)(src + (size_t)i * 8 + 4);
    u16x8 v;
    v[0] = f2bf(a.x); v[1] = f2bf(a.y); v[2] = f2bf(a.z); v[3] = f2bf(a.w);
    v[4] = f2bf(b.x); v[5] = f2bf(b.y); v[6] = f2bf(b.z); v[7] = f2bf(b.w);
    *(u16x8*)(dst + (size_t)i * 8) = v;
}

// Stage 16 edges x 128 dims (one half of the concat input) into LDS A-frag layout.
__device__ __forceinline__ void stage_half(const float* __restrict__ row, int lane, u16* buf) {
    int m = lane >> 2, q = lane & 3;
    const float* seg = row + q * 32;
#pragma unroll
    for (int i = 0; i < 4; i++) {
        float4 a = *(const float4*)(seg + i * 8);
        float4 b = *(const float4*)(seg + i * 8 + 4);
        u16x8 v;
        v[0] = f2bf(a.x); v[1] = f2bf(a.y); v[2] = f2bf(a.z); v[3] = f2bf(a.w);
        v[4] = f2bf(b.x); v[5] = f2bf(b.y); v[6] = f2bf(b.z); v[7] = f2bf(b.w);
        *(u16x8*)(buf + ((q * 4 + i) * 16 + m) * 8) = v;
    }
}

// 16x128 tile GEMM over K = KT*32; A frags from LDS, B frags from swizzled weights.
template <int KT>
__device__ __forceinline__ void gemm_tile(const u16* aLDS, const u16* __restrict__ Wg,
                                          int lq, int ln, f32x4 acc[8]) {
#pragma unroll
    for (int kt = 0; kt < KT; kt++) {
        bf16x8 af = *(const bf16x8*)(aLDS + ((kt * 4 + lq) * 16 + ln) * 8);
#pragma unroll
        for (int nt = 0; nt < 8; nt++) {
            bf16x8 bfv = *(const bf16x8*)(Wg + (size_t)((kt * 4 + lq) * 128 + nt * 16 + ln) * 8);
            acc[nt] = __builtin_amdgcn_mfma_f32_16x16x32_bf16(af, bfv, acc[nt], 0, 0, 0);
        }
    }
}

// relu(acc) -> LDS bf16 A-frag layout (next GEMM's A).
__device__ __forceinline__ void store_h_relu(const f32x4 acc[8], u16* buf, int lq, int ln) {
#pragma unroll
    for (int nt = 0; nt < 8; nt++)
#pragma unroll
        for (int reg = 0; reg < 4; reg++) {
            float h = fmaxf(acc[nt][reg], 0.f);
            int dcol = nt * 16 + ln;
            int r = lq * 4 + reg;
            buf[((dcol >> 3) * 16 + r) * 8 + (dcol & 7)] = f2bf(h);
        }
}

// One 2-layer MLP over concat([u[src],i[dst]]) staged as two K=128 halves.
__device__ __forceinline__ void mlp(const float* __restrict__ uF, const float* __restrict__ iF,
                                    const int* __restrict__ srcI, const int* __restrict__ dstI,
                                    int ebase, int lane, int lq, int ln,
                                    const u16* __restrict__ w1, const u16* __restrict__ w2,
                                    u16* bufA, u16* bufB, f32x4 acc[8]) {
    int e = ebase + (lane >> 2);
    int su = srcI[e], sd = dstI[e];
    f32x4 h1[8];
#pragma unroll
    for (int nt = 0; nt < 8; nt++) h1[nt] = (f32x4){0.f, 0.f, 0.f, 0.f};

    stage_half(uF + (size_t)su * D_, lane, bufA);
    __syncthreads();
    gemm_tile<4>(bufA, w1, lq, ln, h1);               // K 0..127
    __syncthreads();
    stage_half(iF + (size_t)sd * D_, lane, bufA);
    __syncthreads();
    gemm_tile<4>(bufA, w1 + 16384, lq, ln, h1);       // K 128..255
    store_h_relu(h1, bufB, lq, ln);
    __syncthreads();
    gemm_tile<4>(bufB, w2, lq, ln, acc);
}

__device__ __forceinline__ float softplus_(float x) {
    return fmaxf(x, 0.f) + log1pf(expf(-fabsf(x)));
}

// launch_bounds evidence: (256,3) -> 84 VGPR no spill; (256,4)/(256,5) under-
// allocate (64/48 VGPR) and spill 104/290 MB. Keep (256,3).
template <bool EB>
__global__ __launch_bounds__(256, 3) void fused_kernel(
    const float* __restrict__ urf, const float* __restrict__ irf,
    const float* __restrict__ utf, const float* __restrict__ itf,
    const float* __restrict__ wp, const float* __restrict__ emb,
    const u16* __restrict__ embB,
    const int* __restrict__ srcI, const int* __restrict__ dstI,
    const int* __restrict__ sidI, const int* __restrict__ nsidI,
    const u16* __restrict__ wbuf, float* __restrict__ loss_acc,
    float* __restrict__ out) {
    __shared__ u16 smem[4 * 4096];        // per wave: bufA 2048 + bufB 2048 u16 (8 KB)
    const int tid = threadIdx.x;
    const int w = tid >> 6;
    const int lane = tid & 63;
    const int lq = lane >> 4;
    const int ln = lane & 15;
    u16* bufA = smem + w * 4096;
    u16* bufB = bufA + 2048;
    const int ebase = blockIdx.x * 64 + w * 16;

    // ---------- rating path ----------
    f32x4 rh[8];
#pragma unroll
    for (int nt = 0; nt < 8; nt++) rh[nt] = (f32x4){0.f, 0.f, 0.f, 0.f};
    mlp(urf, irf, srcI, dstI, ebase, lane, lq, ln,
        wbuf + W1R_OFF, wbuf + W2R_OFF, bufA, bufB, rh);

    // ---------- pr = rh @ wp ----------
    {
        float pp[4][5];
#pragma unroll
        for (int r = 0; r < 4; r++)
#pragma unroll
            for (int c = 0; c < 5; c++) pp[r][c] = 0.f;
#pragma unroll
        for (int nt = 0; nt < 8; nt++) {
            int d = nt * 16 + ln;
            float wpc[5];
#pragma unroll
            for (int c = 0; c < 5; c++) wpc[c] = wp[d * 5 + c];
#pragma unroll
            for (int reg = 0; reg < 4; reg++)
#pragma unroll
                for (int c = 0; c < 5; c++) pp[reg][c] += rh[nt][reg] * wpc[c];
        }
#pragma unroll
        for (int off = 1; off < 16; off <<= 1)
#pragma unroll
            for (int reg = 0; reg < 4; reg++)
#pragma unroll
                for (int c = 0; c < 5; c++)
                    pp[reg][c] += __shfl_xor(pp[reg][c], off, 64);
        if (ln == 0) {
#pragma unroll
            for (int reg = 0; reg < 4; reg++) {
                int e = ebase + lq * 4 + reg;
#pragma unroll
                for (int c = 0; c < 5; c++) out[(size_t)e * 5 + c] = pp[reg][c];
            }
        }
    }

    // ---------- topic path (residual) ----------
    __syncthreads();
    f32x4 th[8];
#pragma unroll
    for (int nt = 0; nt < 8; nt++) th[nt] = rh[nt];
    mlp(utf, itf, srcI, dstI, ebase, lane, lq, ln,
        wbuf + W1T_OFF, wbuf + W2T_OFF, bufA, bufB, th);

    // th -> LDS f32 (16x128 = 8 KB, overlays bufA+bufB)
    __syncthreads();
    float* thb = (float*)bufA;
    if constexpr (EB) {
        // review layout: thb[(r*16 + (dim>>3))*8 + (dim&7)] = th[r][dim]
#pragma unroll
        for (int nt = 0; nt < 8; nt++)
#pragma unroll
            for (int reg = 0; reg < 4; reg++) {
                int col = nt * 16 + ln;
                thb[((lq * 4 + reg) * 16 + (col >> 3)) * 8 + (col & 7)] = th[nt][reg];
            }
    } else {
#pragma unroll
        for (int nt = 0; nt < 8; nt++)
#pragma unroll
            for (int reg = 0; reg < 4; reg++)
                thb[(lq * 4 + reg) * 128 + nt * 16 + ln] = th[nt][reg];
    }
    __syncthreads();

    // ---------- review gather + scores + loss ----------
    float wave_loss = 0.f;
    if constexpr (EB) {
        // quarter-wave per edge: 16 lanes x 16 B = one 256 B bf16 row/group;
        // 4 edges in flight per wave load instruction.
        const int g = lane >> 4, gl = lane & 15;
        for (int it = 0; it < 4; it++) {
            int m = it * 4 + g;
            int e = ebase + m;
            float th8[8];
            *(f32x4*)th8       = *(const f32x4*)(thb + (m * 16 + gl) * 8);
            *(f32x4*)(th8 + 4) = *(const f32x4*)(thb + (m * 16 + gl) * 8 + 4);
            float ps = 0.f, ns = 0.f;
            int pcnt = 0, ncnt = 0;
#pragma unroll
            for (int i = 0; i < L_; i++) {
                int s = sidI[e * L_ + i];
                pcnt += (s > 0) ? 1 : 0;
                union { u16x8 v; unsigned int u[4]; } cv;
                cv.v = *(const u16x8*)(embB + (size_t)s * D_ + gl * 8);
#pragma unroll
                for (int k = 0; k < 4; k++) {
                    ps = fmaf(th8[2 * k],     bflo(cv.u[k]), ps);
                    ps = fmaf(th8[2 * k + 1], bfhi(cv.u[k]), ps);
                }
            }
#pragma unroll
            for (int i = 0; i < L_; i++) {
                int s = nsidI[e * L_ + i];
                ncnt += (s > 0) ? 1 : 0;
                union { u16x8 v; unsigned int u[4]; } cv;
                cv.v = *(const u16x8*)(embB + (size_t)s * D_ + gl * 8);
#pragma unroll
                for (int k = 0; k < 4; k++) {
                    ns = fmaf(th8[2 * k],     bflo(cv.u[k]), ns);
                    ns = fmaf(th8[2 * k + 1], bfhi(cv.u[k]), ns);
                }
            }
#pragma unroll
            for (int off = 1; off < 16; off <<= 1) {
                ps += __shfl_xor(ps, off, 64);
                ns += __shfl_xor(ns, off, 64);
            }
            if (gl == 0) {
                ps /= ((float)pcnt + 1e-9f);
                ns /= ((float)ncnt + 1e-9f);
                wave_loss += softplus_(ns - ps);
            }
        }
        wave_loss += __shfl_xor(wave_loss, 16, 64);
        wave_loss += __shfl_xor(wave_loss, 32, 64);
    } else {
        const int h = lane >> 5, hl = lane & 31;
        for (int mp = 0; mp < 16; mp += 2) {
            int m = mp + h;
            int e = ebase + m;
            float4 t4 = *(const float4*)(thb + m * 128 + hl * 4);
            float ps = 0.f, ns = 0.f;
            int pcnt = 0, ncnt = 0;
#pragma unroll
            for (int i = 0; i < L_; i++) {
                int s = sidI[e * L_ + i];
                pcnt += (s > 0) ? 1 : 0;
                float4 ev = *(const float4*)(emb + (size_t)s * D_ + hl * 4);
                ps += t4.x * ev.x + t4.y * ev.y + t4.z * ev.z + t4.w * ev.w;
            }
#pragma unroll
            for (int i = 0; i < L_; i++) {
                int s = nsidI[e * L_ + i];
                ncnt += (s > 0) ? 1 : 0;
                float4 ev = *(const float4*)(emb + (size_t)s * D_ + hl * 4);
                ns += t4.x * ev.x + t4.y * ev.y + t4.z * ev.z + t4.w * ev.w;
            }
#pragma unroll
            for (int off = 1; off < 32; off <<= 1) {
                ps += __shfl_xor(ps, off, 64);
                ns += __shfl_xor(ns, off, 64);
            }
            if (hl == 0) {
                ps /= ((float)pcnt + 1e-9f);
                ns /= ((float)ncnt + 1e-9f);
                wave_loss += softplus_(ns - ps);
            }
        }
        wave_loss += __shfl_xor(wave_loss, 32, 64);
    }
    if (lane == 0) atomicAdd(loss_acc, wave_loss);
}

__global__ void finish_kernel(const float* __restrict__ loss_acc, float* __restrict__ out) {
    float v = loss_acc[0] * (1.0f / (float)E_);
    out[(size_t)E_ * C_]     = v;
    out[(size_t)E_ * C_ + 1] = v;
}

extern "C" void kernel_launch(void* const* d_in, const int* in_sizes, int n_in,
                              void* d_out, int out_size, void* d_ws, size_t ws_size,
                              hipStream_t stream) {
    const float* urf = (const float*)d_in[0];
    const float* irf = (const float*)d_in[1];
    const float* utf = (const float*)d_in[2];
    const float* itf = (const float*)d_in[3];
    const float* w1r = (const float*)d_in[4];
    const float* w2r = (const float*)d_in[5];
    const float* w1t = (const float*)d_in[6];
    const float* w2t = (const float*)d_in[7];
    const float* wp  = (const float*)d_in[8];
    const float* emb = (const float*)d_in[9];
    const int* srcI  = (const int*)d_in[10];
    const int* dstI  = (const int*)d_in[11];
    const int* sidI  = (const int*)d_in[12];
    const int* nsidI = (const int*)d_in[13];
    float* out = (float*)d_out;

    float* loss_acc = (float*)d_ws;
    u16* wbuf = (u16*)((char*)d_ws + 256);
    u16* embB = (u16*)((char*)d_ws + EMB_BYTE_OFF);

    bool eb = ws_size >= (size_t)EMB_BYTE_OFF + (size_t)EMB_ELEMS * 2;

    prep_kernel<<<(WTOT + 255) / 256, 256, 0, stream>>>(w1r, w2r, w1t, w2t, wbuf, loss_acc);
    if (eb)
        cvt_kernel<<<(EMB_ELEMS / 8 + 255) / 256, 256, 0, stream>>>(emb, embB, EMB_ELEMS / 8);

    if (eb)
        fused_kernel<true><<<E_ / 64, 256, 0, stream>>>(
            urf, irf, utf, itf, wp, emb, embB,
            srcI, dstI, sidI, nsidI, wbuf, loss_acc, out);
    else
        fused_kernel<false><<<E_ / 64, 256, 0, stream>>>(
            urf, irf, utf, itf, wp, emb, embB,
            srcI, dstI, sidI, nsidI, wbuf, loss_acc, out);

    finish_kernel<<<1, 1, 0, stream>>>(loss_acc, out);
}